// Round 6
// baseline (244.661 us; speedup 1.0000x reference)
//
#include <hip/hip_runtime.h>
#include <math.h>

#define C 320
#define NPTS 2048
#define SUPPTS 20480   // 2*5*2048 support points
#define QPTS 4096      // 2*2048 query points
#define KP 100         // prototypes per problem
#define NCLS 3
#define PSTRIDE 300    // transposed proto row stride (floats)

// ---------------- kernel 1: fused seed-find + gather + self-norm -> pbufT[c][300] ----------------
// [verbatim, PASSED]
__global__ __launch_bounds__(64) void k_protoseed(const float* __restrict__ sup,
                                                  const int* __restrict__ sy,
                                                  float* __restrict__ pbufT) {
    int p    = blockIdx.x;     // 0..299
    int lane = threadIdx.x;
    int prob = (p < 100) ? 2 : ((p < 200) ? 0 : 1);
    int rank = (p < 100) ? p : ((p < 200) ? p - 100 : p - 200);
    int M    = (prob == 2) ? SUPPTS : 10240;
    int base = (prob == 1) ? 10240 : 0;
    int found = 0, sp = 0;
    for (int chunk = 0; chunk < M; chunk += 64) {
        int yy = sy[base + chunk + lane];
        int m  = (prob == 2) ? (1 - yy) : yy;
        unsigned long long bal = __ballot(m != 0);
        int cnt = __popcll(bal);
        if (found + cnt > rank) {
            int need = rank - found;
            int prefix = __popcll(bal & ((1ull << lane) - 1ull));
            unsigned long long match = __ballot(m && (prefix == need));
            int pos = __ffsll((unsigned long long)match) - 1;
            sp = base + chunk + pos;
            break;
        }
        found += cnt;
    }
    const float* fb = sup + ((size_t)(sp >> 11) * C) * NPTS + (sp & 2047);
    float v[5]; float s = 0.f;
    #pragma unroll
    for (int i = 0; i < 5; i++) {
        v[i] = fb[(size_t)(lane + i * 64) * NPTS];
        s += v[i] * v[i];
    }
    #pragma unroll
    for (int off = 32; off > 0; off >>= 1) s += __shfl_down(s, off);
    s = __shfl(s, 0);
    float r = 1.0f / (sqrtf(s) + 1e-8f);
    #pragma unroll
    for (int i = 0; i < 5; i++)
        pbufT[(size_t)(lane + i * 64) * PSTRIDE + p] = v[i] * r;
}

// ---------------- kernel 2: sim max — per-point fg/bg SELECTED, 10 tiles x 10 protos ----------------
// grid (80, 10), block 256. [verbatim r2, PASSED — bank-disjoint fg/bg halves]
__global__ __launch_bounds__(256) void k_assign(const float* __restrict__ sup,
                                                const int* __restrict__ sy,
                                                const float* __restrict__ pbT,
                                                float* __restrict__ pmaxv,
                                                int* __restrict__ pmaxj) {
    __shared__ float shp[2 * C * 12 + 16];   // fg rows at 0, bg rows at C*12+16
    int b = blockIdx.x, jt = blockIdx.y, tid = threadIdx.x;
    int w = (b >= 40) ? 1 : 0;            // 256*40 = 10240 -> way boundary
    int colf = 100 + w * 100 + jt * 10;   // fg protos of this way
    int colb = jt * 10;                   // bg protos
    const int BGOFF = C * 12 + 16;
    for (int i = tid; i < C * 10; i += 256) {
        int c = i / 10, j = i % 10;
        shp[c * 12 + j]         = pbT[(size_t)c * PSTRIDE + colf + j];
        shp[BGOFF + c * 12 + j] = pbT[(size_t)c * PSTRIDE + colb + j];
    }
    int g = b * 256 + tid;                // 0..20479
    int sel = sy[g] ? 0 : BGOFF;          // lane-variant: fg half or bg half
    __syncthreads();
    const float* fb = sup + ((size_t)(g >> 11) * C) * NPTS + (g & 2047);
    float acc[10];
    #pragma unroll
    for (int j = 0; j < 10; j++) acc[j] = 0.f;
    float pf[8];
    #pragma unroll
    for (int k = 0; k < 8; k++) pf[k] = fb[(size_t)k * NPTS];
    for (int cc = 0; cc < C; cc += 8) {
        float cur[8];
        #pragma unroll
        for (int k = 0; k < 8; k++) cur[k] = pf[k];
        if (cc + 8 < C) {
            #pragma unroll
            for (int k = 0; k < 8; k++) pf[k] = fb[(size_t)(cc + 8 + k) * NPTS];
        }
        #pragma unroll
        for (int k = 0; k < 8; k++) {
            const float* row = &shp[sel + (cc + k) * 12];
            float4 p0 = ((const float4*)row)[0];
            float4 p1 = ((const float4*)row)[1];
            float2 p2 = *(const float2*)(row + 8);
            float px = cur[k];
            acc[0] += px * p0.x; acc[1] += px * p0.y;
            acc[2] += px * p0.z; acc[3] += px * p0.w;
            acc[4] += px * p1.x; acc[5] += px * p1.y;
            acc[6] += px * p1.z; acc[7] += px * p1.w;
            acc[8] += px * p2.x; acc[9] += px * p2.y;
        }
    }
    float bv = acc[0]; int bj = 0;
    #pragma unroll
    for (int j = 1; j < 10; j++) {
        if (acc[j] > bv) { bv = acc[j]; bj = j; }
    }
    // layout [jt][20480]: consecutive lanes -> consecutive addrs, fully coalesced
    size_t a0 = (size_t)jt * 20480 + g;
    pmaxv[a0] = bv;
    pmaxj[a0] = jt * 10 + bj;
}

// ---------------- kernel 3: combine 10 tiles -> per-point destination bin (0..299); init loss/csum ----------------
__global__ __launch_bounds__(256) void k_combine_dst(const float* __restrict__ pmaxv,
                                                     const int* __restrict__ pmaxj,
                                                     const int* __restrict__ sy,
                                                     int* __restrict__ dst,
                                                     float* __restrict__ loss) {
    int g = blockIdx.x * 256 + threadIdx.x;   // 0..20479
    if (g == 0) loss[0] = 0.f;
    if (g == 1) loss[1] = 0.f;                // csum accumulator
    float bv = pmaxv[g]; int bj = pmaxj[g];
    #pragma unroll
    for (int t = 1; t < 10; t++) {
        float v = pmaxv[(size_t)t * 20480 + g];
        if (v > bv) { bv = v; bj = pmaxj[(size_t)t * 20480 + g]; }
    }
    int way = (g >= 10240) ? 1 : 0;
    dst[g] = sy[g] ? (100 + way * 100 + bj) : bj;
}

// ---------------- kernel 4: LDS-binned accumulation, 4 parity copies. grid (20, 8) ----------------
// r6 RESTRUCTURE: dispatch-rate experiment. r2/r3/r4/r5 — four structurally different
// inner loops — all measured 50.7±0.3us with identical counters; per-pipe arithmetic
// (DS ~2K cyc/CU, VALU ~0, HBM ~3us) says the datapath work is <10us. The only shared
// structural property was the grid: 800 x 29KB-LDS workgroups (~60ns/block across the
// whole app matches every kernel's duration). So: 5x fewer blocks, each looping over
// 5 ct-passes with the SAME math tree. part/cnt interfaces byte-identical ->
// k_reduce_proto unchanged. dst/dreg loaded once per block (ct-independent).
__global__ __launch_bounds__(256) void k_accum_lds(const float* __restrict__ sup,
                                                   const int* __restrict__ dst,
                                                   float* __restrict__ part,
                                                   float* __restrict__ cnt) {
    __shared__ float bins[8 * 800];   // [cl][copy][bin]: cl*800 + copy*200 + bin
    __shared__ float scnt[800];       // [copy][bin]
    int bx = blockIdx.x;     // slot = ws*2 + half  (0..19)
    int by = blockIdx.y;     // ct-group 0..7 (5 ct each)
    int tid = threadIdx.x;
    int copy = tid & 3;
    int ws = bx >> 1, half = bx & 1;
    int w = (ws >= 5) ? 1 : 0;
    int nbase = half * 1024;

    // dst depends only on the point, not ct: load once per block
    int4 d4 = *(const int4*)(dst + ws * 2048 + nbase + 4 * tid);
    int dreg[4];
    dreg[0] = (d4.x < 100) ? d4.x : (d4.x - w * 100);   // local bin 0..199
    dreg[1] = (d4.y < 100) ? d4.y : (d4.y - w * 100);
    dreg[2] = (d4.z < 100) ? d4.z : (d4.z - w * 100);
    dreg[3] = (d4.w < 100) ? d4.w : (d4.w - w * 100);

    if (by == 0) { for (int i = tid; i < 800; i += 256) scnt[i] = 0.f; }

    for (int pass = 0; pass < 5; pass++) {
        int ct = by * 5 + pass;      // 0..39
        // issue this pass's 8 wide loads; zeroing below overlaps the latency
        const float* base = sup + ((size_t)ws * C + ct * 8) * NPTS + nbase + 4 * tid;
        float4 rv[8];
        #pragma unroll
        for (int cl = 0; cl < 8; cl++)
            rv[cl] = *(const float4*)(base + (size_t)cl * NPTS);

        if (pass > 0) __syncthreads();            // write-phase readers done before re-zero
        for (int i = tid; i < 8 * 800; i += 256) bins[i] = 0.f;
        __syncthreads();

        if (by == 0 && pass == 0) {
            #pragma unroll
            for (int sub = 0; sub < 4; sub++) unsafeAtomicAdd(&scnt[copy * 200 + dreg[sub]], 1.0f);
        }
        #pragma unroll
        for (int cl = 0; cl < 8; cl++) {
            unsafeAtomicAdd(&bins[cl * 800 + copy * 200 + dreg[0]], rv[cl].x);
            unsafeAtomicAdd(&bins[cl * 800 + copy * 200 + dreg[1]], rv[cl].y);
            unsafeAtomicAdd(&bins[cl * 800 + copy * 200 + dreg[2]], rv[cl].z);
            unsafeAtomicAdd(&bins[cl * 800 + copy * 200 + dreg[3]], rv[cl].w);
        }
        __syncthreads();

        float* pout = part + (size_t)(bx * 40 + ct) * 1600;
        for (int i = tid; i < 8 * 200; i += 256) {
            int bin = i >> 3, cl = i & 7;
            float s = bins[cl * 800 + bin] + bins[cl * 800 + 200 + bin]
                    + bins[cl * 800 + 400 + bin] + bins[cl * 800 + 600 + bin];
            pout[i] = s;                          // coalesced write, layout [bin][cl]
        }
    }
    if (by == 0 && tid < 200)
        cnt[bx * 200 + tid] = scnt[tid] + scnt[200 + tid] + scnt[400 + tid] + scnt[600 + tid];
}

// ---------------- kernel 5: reduce partials + mean + l2norm -> phatT[c][300] ----------------
// [verbatim, PASSED]
__global__ __launch_bounds__(64) void k_reduce_proto(const float* __restrict__ part,
                                                     const float* __restrict__ cnt,
                                                     float* __restrict__ phatT) {
    int d   = blockIdx.x;    // 0..299
    int tid = threadIdx.x;
    int local, s0, ns;
    if (d < 100)      { local = d;       s0 = 0;  ns = 20; }
    else if (d < 200) { local = d;       s0 = 0;  ns = 10; }  // fg way0 (slots 0..9)
    else              { local = d - 100; s0 = 10; ns = 10; }  // fg way1 (slots 10..19)
    float dn = 0.f;
    for (int k = 0; k < ns; k++) dn += cnt[(s0 + k) * 200 + local];
    float inv = 1.0f / (dn + 1e-8f);
    float vals[5]; float sq = 0.f;
    #pragma unroll
    for (int i = 0; i < 5; i++) {
        int c = tid + i * 64;
        int ct = c >> 3, cl = c & 7;
        float s = 0.f;
        for (int k = 0; k < ns; k++)
            s += part[(size_t)((s0 + k) * 40 + ct) * 1600 + local * 8 + cl];
        float v = s * inv;
        vals[i] = v; sq += v * v;
    }
    #pragma unroll
    for (int off = 32; off > 0; off >>= 1) sq += __shfl_down(sq, off);
    sq = __shfl(sq, 0);
    float rn = 1.0f / (sqrtf(sq) + 1e-8f);
    #pragma unroll
    for (int i = 0; i < 5; i++)
        phatT[(size_t)(tid + i * 64) * PSTRIDE + d] = vals[i] * rn;
}

// ---------------- kernel 6: query sim max, split-channel 4 waves, + fused query norm ----------------
// grid (16, 30), block 256. [verbatim, PASSED]
__global__ __launch_bounds__(256) void k_qpartial(const float* __restrict__ qry,
                                                  const float* __restrict__ phT,
                                                  float* __restrict__ qmaxv,
                                                  float* __restrict__ qrn) {
    __shared__ float shp[C * 16];
    __shared__ float red[3 * 64 * 45];     // 40 accs + 4 qn partials, stride 45
    int pb = blockIdx.x, jt = blockIdx.y, tid = threadIdx.x;
    int wave = tid >> 6, lane = tid & 63;
    int j0 = jt * 10;
    for (int i = tid; i < C * 10; i += 256) {
        int j = i % 10, c = i / 10;
        shp[c * 16 + j] = phT[(size_t)c * PSTRIDE + j0 + j];
    }
    __syncthreads();
    int m = pb * 256 + lane * 4;    // 0..4095
    int c0 = wave * 80;
    const float* fb = qry + ((size_t)(m >> 11) * C + c0) * NPTS + (m & 2047);
    float acc[4][10];
    #pragma unroll
    for (int p = 0; p < 4; p++)
        #pragma unroll
        for (int j = 0; j < 10; j++) acc[p][j] = 0.f;
    float qn[4] = {0.f, 0.f, 0.f, 0.f};
    float4 pf[8];
    #pragma unroll
    for (int k = 0; k < 8; k++) pf[k] = *(const float4*)(fb + (size_t)k * NPTS);
    for (int cc = 0; cc < 80; cc += 8) {
        float4 cur[8];
        #pragma unroll
        for (int k = 0; k < 8; k++) cur[k] = pf[k];
        if (cc + 8 < 80) {
            #pragma unroll
            for (int k = 0; k < 8; k++) pf[k] = *(const float4*)(fb + (size_t)(cc + 8 + k) * NPTS);
        }
        #pragma unroll
        for (int k = 0; k < 8; k++) {
            const float* row = &shp[(c0 + cc + k) * 16];
            float4 p0 = ((const float4*)row)[0];
            float4 p1 = ((const float4*)row)[1];
            float2 p2 = ((const float2*)row)[4];
            float pr[10] = {p0.x,p0.y,p0.z,p0.w,p1.x,p1.y,p1.z,p1.w,p2.x,p2.y};
            float4 cv = cur[k];
            if (jt == 0) {
                qn[0] += cv.x*cv.x; qn[1] += cv.y*cv.y; qn[2] += cv.z*cv.z; qn[3] += cv.w*cv.w;
            }
            #pragma unroll
            for (int j = 0; j < 10; j++) {
                acc[0][j] += cv.x * pr[j];
                acc[1][j] += cv.y * pr[j];
                acc[2][j] += cv.z * pr[j];
                acc[3][j] += cv.w * pr[j];
            }
        }
    }
    if (wave > 0) {
        float* my = red + ((wave - 1) * 64 + lane) * 45;
        #pragma unroll
        for (int p = 0; p < 4; p++)
            #pragma unroll
            for (int j = 0; j < 10; j++) my[p * 10 + j] = acc[p][j];
        #pragma unroll
        for (int p = 0; p < 4; p++) my[40 + p] = qn[p];
    }
    __syncthreads();
    if (wave == 0) {
        #pragma unroll
        for (int w = 0; w < 3; w++) {
            const float* my = red + (w * 64 + lane) * 45;
            #pragma unroll
            for (int p = 0; p < 4; p++)
                #pragma unroll
                for (int j = 0; j < 10; j++) acc[p][j] += my[p * 10 + j];
            #pragma unroll
            for (int p = 0; p < 4; p++) qn[p] += my[40 + p];
        }
        #pragma unroll
        for (int p = 0; p < 4; p++) {
            float bv = acc[p][0];
            #pragma unroll
            for (int j = 1; j < 10; j++) bv = fmaxf(bv, acc[p][j]);
            qmaxv[(size_t)(m + p) * 30 + jt] = bv;
        }
        if (jt == 0) {
            #pragma unroll
            for (int p = 0; p < 4; p++) qrn[m + p] = 1.0f / (sqrtf(qn[p]) + 1e-8f);
        }
    }
}

// ---------------- kernel 7: per-class max, softmax CE, write pred + conf/label staging ----------------
__global__ __launch_bounds__(256) void k_pred(const float* __restrict__ qmaxv,
                                              const float* __restrict__ qrn,
                                              const int* __restrict__ qy,
                                              float* __restrict__ out,
                                              float* __restrict__ lossacc,
                                              float* __restrict__ cbuf,
                                              int* __restrict__ lbuf) {
    __shared__ float redL[256];
    __shared__ float redC[256];
    int tid = threadIdx.x;
    int m = blockIdx.x * 256 + tid;  // 0..4095
    float rn = qrn[m];
    float pred[NCLS];
    #pragma unroll
    for (int cls = 0; cls < NCLS; cls++) {
        float g = qmaxv[(size_t)m * 30 + cls * 10];
        #pragma unroll
        for (int t = 1; t < 10; t++) g = fmaxf(g, qmaxv[(size_t)m * 30 + cls * 10 + t]);
        pred[cls] = rn * g;
    }
    int q = m >> 11, n = m & 2047;
    #pragma unroll
    for (int cls = 0; cls < NCLS; cls++)
        out[1 + ((size_t)(q * NCLS + cls)) * NPTS + n] = pred[cls];
    float mx = fmaxf(pred[0], fmaxf(pred[1], pred[2]));
    float lse = mx + logf(expf(pred[0] - mx) + expf(pred[1] - mx) + expf(pred[2] - mx));
    int lab = 0; float cf = pred[0];
    if (pred[1] > cf) { cf = pred[1]; lab = 1; }
    if (pred[2] > cf) { cf = pred[2]; lab = 2; }
    cbuf[m] = cf; lbuf[m] = lab;
    redL[tid] = lse - pred[qy[m]];
    redC[tid] = cf;
    __syncthreads();
    for (int off = 128; off > 0; off >>= 1) {
        if (tid < off) { redL[tid] += redL[tid + off]; redC[tid] += redC[tid + off]; }
        __syncthreads();
    }
    if (tid == 0) {
        atomicAdd(&lossacc[0], redL[0]);
        atomicAdd(&lossacc[1], redC[0]);
    }
}

// ---------------- kernel 8: final labels + loss. grid 16 x 256, fully coalesced ----------------
__global__ __launch_bounds__(256) void k_final(const float* __restrict__ cbuf,
                                               const int* __restrict__ lbuf,
                                               const float* __restrict__ lossacc,
                                               float* __restrict__ out) {
    int m = blockIdx.x * 256 + threadIdx.x;   // 0..4095
    float mean = lossacc[1] / (float)QPTS;
    float cf = cbuf[m];
    out[1 + 2 * NCLS * NPTS + m] = (cf > mean) ? (float)lbuf[m] : -1.0f;
    if (m == 0) out[0] = 2.0f * lossacc[0] / (float)QPTS;
}

extern "C" void kernel_launch(void* const* d_in, const int* in_sizes, int n_in,
                              void* d_out, int out_size, void* d_ws, size_t ws_size,
                              hipStream_t stream) {
    const float* sup = (const float*)d_in[0];   // [2,5,320,2048]
    const float* qry = (const float*)d_in[1];   // [2,320,2048]
    const int*   sy  = (const int*)d_in[2];     // [2,5,2048]
    const int*   qy  = (const int*)d_in[3];     // [2,2048]
    float* out = (float*)d_out;

    // workspace layout — persistent region, then transient overlay region
    float* f      = (float*)d_ws;
    float* qrn    = f;                     // 4096
    float* cnt    = qrn + QPTS;            // 4000
    float* pbufT  = cnt + 4000;            // 96000
    float* phatT  = pbufT + 96000;         // 96000
    float* loss   = phatT + 96000;         // 4 (loss[0], csum=loss[1])
    int*   dstb   = (int*)(loss + 4);      // 20480
    float* trans  = (float*)(dstb + SUPPTS);
    // phase A (assign+combine): pmaxv[204800] + pmaxj[204800], layout [10][20480]
    float* pmaxv  = trans;
    int*   pmaxj  = (int*)(pmaxv + 204800);
    // phase B (accum+reduce): part[1,280,000] overlays phase A
    float* part   = trans;
    // phase C (qpartial..final): qmaxv[122880] + cbuf[4096] + lbuf[4096] overlays again
    float* qmaxv  = trans;
    float* cbuf   = qmaxv + 122880;
    int*   lbuf   = (int*)(cbuf + QPTS);

    k_protoseed<<<300, 64, 0, stream>>>(sup, sy, pbufT);
    {
        dim3 grid(80, 10);
        k_assign<<<grid, 256, 0, stream>>>(sup, sy, pbufT, pmaxv, pmaxj);
    }
    k_combine_dst<<<80, 256, 0, stream>>>(pmaxv, pmaxj, sy, dstb, loss);
    {
        dim3 grid(20, 8);
        k_accum_lds<<<grid, 256, 0, stream>>>(sup, dstb, part, cnt);
    }
    k_reduce_proto<<<300, 64, 0, stream>>>(part, cnt, phatT);
    {
        dim3 grid(16, 30);
        k_qpartial<<<grid, 256, 0, stream>>>(qry, phatT, qmaxv, qrn);
    }
    k_pred<<<16, 256, 0, stream>>>(qmaxv, qrn, qy, out, loss, cbuf, lbuf);
    k_final<<<16, 256, 0, stream>>>(cbuf, lbuf, loss, out);
}

// Round 8
// 203.210 us; speedup vs baseline: 1.2040x; 1.2040x over previous
//
#include <hip/hip_runtime.h>
#include <math.h>

#define C 320
#define NPTS 2048
#define SUPPTS 20480   // 2*5*2048 support points
#define QPTS 4096      // 2*2048 query points
#define KP 100         // prototypes per problem
#define NCLS 3
#define PSTRIDE 300    // transposed proto row stride (floats)

// ---------------- kernel 1: fused seed-find + gather + self-norm -> pbufT[c][300] ----------------
// [verbatim except: lane 0 zeroes cntG[p] for the global count path]
__global__ __launch_bounds__(64) void k_protoseed(const float* __restrict__ sup,
                                                  const int* __restrict__ sy,
                                                  float* __restrict__ pbufT,
                                                  int* __restrict__ cntG) {
    int p    = blockIdx.x;     // 0..299
    int lane = threadIdx.x;
    if (lane == 0) cntG[p] = 0;          // zero per-bin counts (filled by k_combine)
    int prob = (p < 100) ? 2 : ((p < 200) ? 0 : 1);
    int rank = (p < 100) ? p : ((p < 200) ? p - 100 : p - 200);
    int M    = (prob == 2) ? SUPPTS : 10240;
    int base = (prob == 1) ? 10240 : 0;
    int found = 0, sp = 0;
    for (int chunk = 0; chunk < M; chunk += 64) {
        int yy = sy[base + chunk + lane];
        int m  = (prob == 2) ? (1 - yy) : yy;
        unsigned long long bal = __ballot(m != 0);
        int cnt = __popcll(bal);
        if (found + cnt > rank) {
            int need = rank - found;
            int prefix = __popcll(bal & ((1ull << lane) - 1ull));
            unsigned long long match = __ballot(m && (prefix == need));
            int pos = __ffsll((unsigned long long)match) - 1;
            sp = base + chunk + pos;
            break;
        }
        found += cnt;
    }
    const float* fb = sup + ((size_t)(sp >> 11) * C) * NPTS + (sp & 2047);
    float v[5]; float s = 0.f;
    #pragma unroll
    for (int i = 0; i < 5; i++) {
        v[i] = fb[(size_t)(lane + i * 64) * NPTS];
        s += v[i] * v[i];
    }
    #pragma unroll
    for (int off = 32; off > 0; off >>= 1) s += __shfl_down(s, off);
    s = __shfl(s, 0);
    float r = 1.0f / (sqrtf(s) + 1e-8f);
    #pragma unroll
    for (int i = 0; i < 5; i++)
        pbufT[(size_t)(lane + i * 64) * PSTRIDE + p] = v[i] * r;
}

// ---------------- kernel 2: sim max — per-point fg/bg SELECTED, 10 tiles x 10 protos ----------------
// grid (80, 10), block 256. [verbatim r2, PASSED — bank-disjoint fg/bg halves]
__global__ __launch_bounds__(256) void k_assign(const float* __restrict__ sup,
                                                const int* __restrict__ sy,
                                                const float* __restrict__ pbT,
                                                float* __restrict__ pmaxv,
                                                int* __restrict__ pmaxj) {
    __shared__ float shp[2 * C * 12 + 16];   // fg rows at 0, bg rows at C*12+16
    int b = blockIdx.x, jt = blockIdx.y, tid = threadIdx.x;
    int w = (b >= 40) ? 1 : 0;            // 256*40 = 10240 -> way boundary
    int colf = 100 + w * 100 + jt * 10;   // fg protos of this way
    int colb = jt * 10;                   // bg protos
    const int BGOFF = C * 12 + 16;
    for (int i = tid; i < C * 10; i += 256) {
        int c = i / 10, j = i % 10;
        shp[c * 12 + j]         = pbT[(size_t)c * PSTRIDE + colf + j];
        shp[BGOFF + c * 12 + j] = pbT[(size_t)c * PSTRIDE + colb + j];
    }
    int g = b * 256 + tid;                // 0..20479
    int sel = sy[g] ? 0 : BGOFF;          // lane-variant: fg half or bg half
    __syncthreads();
    const float* fb = sup + ((size_t)(g >> 11) * C) * NPTS + (g & 2047);
    float acc[10];
    #pragma unroll
    for (int j = 0; j < 10; j++) acc[j] = 0.f;
    float pf[8];
    #pragma unroll
    for (int k = 0; k < 8; k++) pf[k] = fb[(size_t)k * NPTS];
    for (int cc = 0; cc < C; cc += 8) {
        float cur[8];
        #pragma unroll
        for (int k = 0; k < 8; k++) cur[k] = pf[k];
        if (cc + 8 < C) {
            #pragma unroll
            for (int k = 0; k < 8; k++) pf[k] = fb[(size_t)(cc + 8 + k) * NPTS];
        }
        #pragma unroll
        for (int k = 0; k < 8; k++) {
            const float* row = &shp[sel + (cc + k) * 12];
            float4 p0 = ((const float4*)row)[0];
            float4 p1 = ((const float4*)row)[1];
            float2 p2 = *(const float2*)(row + 8);
            float px = cur[k];
            acc[0] += px * p0.x; acc[1] += px * p0.y;
            acc[2] += px * p0.z; acc[3] += px * p0.w;
            acc[4] += px * p1.x; acc[5] += px * p1.y;
            acc[6] += px * p1.z; acc[7] += px * p1.w;
            acc[8] += px * p2.x; acc[9] += px * p2.y;
        }
    }
    float bv = acc[0]; int bj = 0;
    #pragma unroll
    for (int j = 1; j < 10; j++) {
        if (acc[j] > bv) { bv = acc[j]; bj = j; }
    }
    // layout [jt][20480]: consecutive lanes -> consecutive addrs, fully coalesced
    size_t a0 = (size_t)jt * 20480 + g;
    pmaxv[a0] = bv;
    pmaxj[a0] = jt * 10 + bj;
}

// ---------------- kernel 3: combine 10 tiles -> dst bin; count bins via global int atomics ----------------
__global__ __launch_bounds__(256) void k_combine_dst(const float* __restrict__ pmaxv,
                                                     const int* __restrict__ pmaxj,
                                                     const int* __restrict__ sy,
                                                     int* __restrict__ dst,
                                                     float* __restrict__ loss,
                                                     int* __restrict__ cntG) {
    int g = blockIdx.x * 256 + threadIdx.x;   // 0..20479
    if (g == 0) loss[0] = 0.f;
    if (g == 1) loss[1] = 0.f;                // csum accumulator
    float bv = pmaxv[g]; int bj = pmaxj[g];
    #pragma unroll
    for (int t = 1; t < 10; t++) {
        float v = pmaxv[(size_t)t * 20480 + g];
        if (v > bv) { bv = v; bj = pmaxj[(size_t)t * 20480 + g]; }
    }
    int way = (g >= 10240) ? 1 : 0;
    int dv = sy[g] ? (100 + way * 100 + bj) : bj;
    dst[g] = dv;
    atomicAdd(&cntG[dv], 1);                  // 20480 int atomics total (hardware-native)
}

// ---------------- kernel 4: WAVE-PRIVATE bin accumulation. grid (20, 20) ----------------
// r8 FIX of r7: the r7 dup-fallback (`if (pq==k) mybins[addr]+=f;` x4, identical bodies,
// disjoint exhaustive conditions) is per-thread-equivalent to ONE unpredicated RMW, so
// the compiler legally merged it back into the racy vector RMW -> colliding lanes lost
// updates (~3-6% of iterations) -> protos off ~1% -> preds passed 0.044 but knife-edge
// labels flipped (exactly the observed failure: out0/1 pass, out2 absmax 3).
// Fix: dup case uses unsafeAtomicAdd (native ds_add_f32; cannot be merged; HW
// serializes colliding lanes). Atomics now fire in only ~3-6% of iterations
// (~0.2M lane-atomics vs the original 6.55M that pinned r2-r6 at 50us).
__global__ __launch_bounds__(256) void k_accum_lds(const float* __restrict__ sup,
                                                   const int* __restrict__ dst,
                                                   float* __restrict__ part) {
    __shared__ float bins[4 * 200 * 16];   // [wave][bin][ch]
    __shared__ int   dl[1024];             // local bin (0..199) per point of this slot-half
    int bx = blockIdx.x;     // slot-half = ws*2 + half  (0..19)
    int by = blockIdx.y;     // 16-channel group 0..19, c0 = by*16
    int tid = threadIdx.x;
    int ws = bx >> 1, half = bx & 1;
    int wmask = (ws >= 5) ? 1 : 0;
    int c0 = by * 16;

    // stage local bins (coalesced int4), and zero the private bin arrays
    int4 d4 = *(const int4*)(dst + ws * 2048 + half * 1024 + 4 * tid);
    dl[4 * tid + 0] = (d4.x < 100) ? d4.x : (d4.x - wmask * 100);
    dl[4 * tid + 1] = (d4.y < 100) ? d4.y : (d4.y - wmask * 100);
    dl[4 * tid + 2] = (d4.z < 100) ? d4.z : (d4.z - wmask * 100);
    dl[4 * tid + 3] = (d4.w < 100) ? d4.w : (d4.w - wmask * 100);
    for (int i = tid; i < 4 * 200 * 16; i += 256) bins[i] = 0.f;
    __syncthreads();

    int wv = tid >> 6, lane = tid & 63;
    int ch = lane & 15, pq = lane >> 4;    // 16 channels x 4 points per iteration
    float* mybins = bins + wv * 3200;
    const int* dlp = dl + wv * 256 + pq;
    const float* fb = sup + ((size_t)(ws * C + c0 + ch)) * NPTS + half * 1024 + wv * 256 + pq;

    int   b_cur = dlp[0];
    float f_cur = fb[0];
    for (int it = 0; it < 64; it++) {
        int nidx = (it < 63) ? (it + 1) * 4 : 0;   // prefetch-1 (clamped: dummy re-read at tail)
        int   b_nxt = dlp[nidx];
        float f_nxt = fb[nidx];
        int b0 = __builtin_amdgcn_readlane(b_cur, 0);
        int b1 = __builtin_amdgcn_readlane(b_cur, 16);
        int b2 = __builtin_amdgcn_readlane(b_cur, 32);
        int b3 = __builtin_amdgcn_readlane(b_cur, 48);
        bool dup = (b0 == b1) | (b0 == b2) | (b0 == b3) |
                   (b1 == b2) | (b1 == b3) | (b2 == b3);
        int addr = b_cur * 16 + ch;
        if (!dup) {
            mybins[addr] += f_cur;                 // 64 distinct addrs: plain RMW
        } else {
            unsafeAtomicAdd(&mybins[addr], f_cur); // rare (~3-6%): native ds_add_f32,
        }                                          // HW serializes colliding lanes
        b_cur = b_nxt; f_cur = f_nxt;
    }
    __syncthreads();

    // merge 4 wave-copies -> part, byte-identical interface: [(bx*40+ct8)*1600 + bin*8 + cl]
    for (int i = tid; i < 3200; i += 256) {
        int bin = i >> 4, c = i & 15;
        float s = bins[bin * 16 + c] + bins[3200 + bin * 16 + c]
                + bins[6400 + bin * 16 + c] + bins[9600 + bin * 16 + c];
        int ct8 = by * 2 + (c >> 3);
        part[(size_t)(bx * 40 + ct8) * 1600 + bin * 8 + (c & 7)] = s;
    }
}

// ---------------- kernel 5: reduce partials + mean + l2norm -> phatT[c][300] ----------------
// [verbatim except: dn now comes from cntG[d] (same integer value as the old float sums)]
__global__ __launch_bounds__(64) void k_reduce_proto(const float* __restrict__ part,
                                                     const int* __restrict__ cntG,
                                                     float* __restrict__ phatT) {
    int d   = blockIdx.x;    // 0..299
    int tid = threadIdx.x;
    int local, s0, ns;
    if (d < 100)      { local = d;       s0 = 0;  ns = 20; }
    else if (d < 200) { local = d;       s0 = 0;  ns = 10; }  // fg way0 (slots 0..9)
    else              { local = d - 100; s0 = 10; ns = 10; }  // fg way1 (slots 10..19)
    float dn = (float)cntG[d];
    float inv = 1.0f / (dn + 1e-8f);
    float vals[5]; float sq = 0.f;
    #pragma unroll
    for (int i = 0; i < 5; i++) {
        int c = tid + i * 64;
        int ct = c >> 3, cl = c & 7;
        float s = 0.f;
        for (int k = 0; k < ns; k++)
            s += part[(size_t)((s0 + k) * 40 + ct) * 1600 + local * 8 + cl];
        float v = s * inv;
        vals[i] = v; sq += v * v;
    }
    #pragma unroll
    for (int off = 32; off > 0; off >>= 1) sq += __shfl_down(sq, off);
    sq = __shfl(sq, 0);
    float rn = 1.0f / (sqrtf(sq) + 1e-8f);
    #pragma unroll
    for (int i = 0; i < 5; i++)
        phatT[(size_t)(tid + i * 64) * PSTRIDE + d] = vals[i] * rn;
}

// ---------------- kernel 6: query sim max, split-channel 4 waves, + fused query norm ----------------
// grid (16, 30), block 256. [verbatim, PASSED]
__global__ __launch_bounds__(256) void k_qpartial(const float* __restrict__ qry,
                                                  const float* __restrict__ phT,
                                                  float* __restrict__ qmaxv,
                                                  float* __restrict__ qrn) {
    __shared__ float shp[C * 16];
    __shared__ float red[3 * 64 * 45];     // 40 accs + 4 qn partials, stride 45
    int pb = blockIdx.x, jt = blockIdx.y, tid = threadIdx.x;
    int wave = tid >> 6, lane = tid & 63;
    int j0 = jt * 10;
    for (int i = tid; i < C * 10; i += 256) {
        int j = i % 10, c = i / 10;
        shp[c * 16 + j] = phT[(size_t)c * PSTRIDE + j0 + j];
    }
    __syncthreads();
    int m = pb * 256 + lane * 4;    // 0..4095
    int c0 = wave * 80;
    const float* fb = qry + ((size_t)(m >> 11) * C + c0) * NPTS + (m & 2047);
    float acc[4][10];
    #pragma unroll
    for (int p = 0; p < 4; p++)
        #pragma unroll
        for (int j = 0; j < 10; j++) acc[p][j] = 0.f;
    float qn[4] = {0.f, 0.f, 0.f, 0.f};
    float4 pf[8];
    #pragma unroll
    for (int k = 0; k < 8; k++) pf[k] = *(const float4*)(fb + (size_t)k * NPTS);
    for (int cc = 0; cc < 80; cc += 8) {
        float4 cur[8];
        #pragma unroll
        for (int k = 0; k < 8; k++) cur[k] = pf[k];
        if (cc + 8 < 80) {
            #pragma unroll
            for (int k = 0; k < 8; k++) pf[k] = *(const float4*)(fb + (size_t)(cc + 8 + k) * NPTS);
        }
        #pragma unroll
        for (int k = 0; k < 8; k++) {
            const float* row = &shp[(c0 + cc + k) * 16];
            float4 p0 = ((const float4*)row)[0];
            float4 p1 = ((const float4*)row)[1];
            float2 p2 = ((const float2*)row)[4];
            float pr[10] = {p0.x,p0.y,p0.z,p0.w,p1.x,p1.y,p1.z,p1.w,p2.x,p2.y};
            float4 cv = cur[k];
            if (jt == 0) {
                qn[0] += cv.x*cv.x; qn[1] += cv.y*cv.y; qn[2] += cv.z*cv.z; qn[3] += cv.w*cv.w;
            }
            #pragma unroll
            for (int j = 0; j < 10; j++) {
                acc[0][j] += cv.x * pr[j];
                acc[1][j] += cv.y * pr[j];
                acc[2][j] += cv.z * pr[j];
                acc[3][j] += cv.w * pr[j];
            }
        }
    }
    if (wave > 0) {
        float* my = red + ((wave - 1) * 64 + lane) * 45;
        #pragma unroll
        for (int p = 0; p < 4; p++)
            #pragma unroll
            for (int j = 0; j < 10; j++) my[p * 10 + j] = acc[p][j];
        #pragma unroll
        for (int p = 0; p < 4; p++) my[40 + p] = qn[p];
    }
    __syncthreads();
    if (wave == 0) {
        #pragma unroll
        for (int w = 0; w < 3; w++) {
            const float* my = red + (w * 64 + lane) * 45;
            #pragma unroll
            for (int p = 0; p < 4; p++)
                #pragma unroll
                for (int j = 0; j < 10; j++) acc[p][j] += my[p * 10 + j];
            #pragma unroll
            for (int p = 0; p < 4; p++) qn[p] += my[40 + p];
        }
        #pragma unroll
        for (int p = 0; p < 4; p++) {
            float bv = acc[p][0];
            #pragma unroll
            for (int j = 1; j < 10; j++) bv = fmaxf(bv, acc[p][j]);
            qmaxv[(size_t)(m + p) * 30 + jt] = bv;
        }
        if (jt == 0) {
            #pragma unroll
            for (int p = 0; p < 4; p++) qrn[m + p] = 1.0f / (sqrtf(qn[p]) + 1e-8f);
        }
    }
}

// ---------------- kernel 7: per-class max, softmax CE, write pred + conf/label staging ----------------
__global__ __launch_bounds__(256) void k_pred(const float* __restrict__ qmaxv,
                                              const float* __restrict__ qrn,
                                              const int* __restrict__ qy,
                                              float* __restrict__ out,
                                              float* __restrict__ lossacc,
                                              float* __restrict__ cbuf,
                                              int* __restrict__ lbuf) {
    __shared__ float redL[256];
    __shared__ float redC[256];
    int tid = threadIdx.x;
    int m = blockIdx.x * 256 + tid;  // 0..4095
    float rn = qrn[m];
    float pred[NCLS];
    #pragma unroll
    for (int cls = 0; cls < NCLS; cls++) {
        float g = qmaxv[(size_t)m * 30 + cls * 10];
        #pragma unroll
        for (int t = 1; t < 10; t++) g = fmaxf(g, qmaxv[(size_t)m * 30 + cls * 10 + t]);
        pred[cls] = rn * g;
    }
    int q = m >> 11, n = m & 2047;
    #pragma unroll
    for (int cls = 0; cls < NCLS; cls++)
        out[1 + ((size_t)(q * NCLS + cls)) * NPTS + n] = pred[cls];
    float mx = fmaxf(pred[0], fmaxf(pred[1], pred[2]));
    float lse = mx + logf(expf(pred[0] - mx) + expf(pred[1] - mx) + expf(pred[2] - mx));
    int lab = 0; float cf = pred[0];
    if (pred[1] > cf) { cf = pred[1]; lab = 1; }
    if (pred[2] > cf) { cf = pred[2]; lab = 2; }
    cbuf[m] = cf; lbuf[m] = lab;
    redL[tid] = lse - pred[qy[m]];
    redC[tid] = cf;
    __syncthreads();
    for (int off = 128; off > 0; off >>= 1) {
        if (tid < off) { redL[tid] += redL[tid + off]; redC[tid] += redC[tid + off]; }
        __syncthreads();
    }
    if (tid == 0) {
        atomicAdd(&lossacc[0], redL[0]);
        atomicAdd(&lossacc[1], redC[0]);
    }
}

// ---------------- kernel 8: final labels + loss. grid 16 x 256, fully coalesced ----------------
__global__ __launch_bounds__(256) void k_final(const float* __restrict__ cbuf,
                                               const int* __restrict__ lbuf,
                                               const float* __restrict__ lossacc,
                                               float* __restrict__ out) {
    int m = blockIdx.x * 256 + threadIdx.x;   // 0..4095
    float mean = lossacc[1] / (float)QPTS;
    float cf = cbuf[m];
    out[1 + 2 * NCLS * NPTS + m] = (cf > mean) ? (float)lbuf[m] : -1.0f;
    if (m == 0) out[0] = 2.0f * lossacc[0] / (float)QPTS;
}

extern "C" void kernel_launch(void* const* d_in, const int* in_sizes, int n_in,
                              void* d_out, int out_size, void* d_ws, size_t ws_size,
                              hipStream_t stream) {
    const float* sup = (const float*)d_in[0];   // [2,5,320,2048]
    const float* qry = (const float*)d_in[1];   // [2,320,2048]
    const int*   sy  = (const int*)d_in[2];     // [2,5,2048]
    const int*   qy  = (const int*)d_in[3];     // [2,2048]
    float* out = (float*)d_out;

    // workspace layout — identical offsets to the r2-r6 passing kernels;
    // cntG aliases the dead legacy cnt slot (300 ints fit in its 4000 floats)
    float* f      = (float*)d_ws;
    float* qrn    = f;                     // 4096
    float* cnt    = qrn + QPTS;            // 4000 (legacy slot; first 1200B reused as cntG)
    int*   cntG   = (int*)cnt;             // 300 ints (per-bin point counts)
    float* pbufT  = cnt + 4000;            // 96000
    float* phatT  = pbufT + 96000;         // 96000
    float* loss   = phatT + 96000;         // 4 (loss[0], csum=loss[1])
    int*   dstb   = (int*)(loss + 4);      // 20480
    float* trans  = (float*)(dstb + SUPPTS);
    // phase A (assign+combine): pmaxv[204800] + pmaxj[204800], layout [10][20480]
    float* pmaxv  = trans;
    int*   pmaxj  = (int*)(pmaxv + 204800);
    // phase B (accum+reduce): part[1,280,000] overlays phase A
    float* part   = trans;
    // phase C (qpartial..final): qmaxv[122880] + cbuf[4096] + lbuf[4096] overlays again
    float* qmaxv  = trans;
    float* cbuf   = qmaxv + 122880;
    int*   lbuf   = (int*)(cbuf + QPTS);

    k_protoseed<<<300, 64, 0, stream>>>(sup, sy, pbufT, cntG);
    {
        dim3 grid(80, 10);
        k_assign<<<grid, 256, 0, stream>>>(sup, sy, pbufT, pmaxv, pmaxj);
    }
    k_combine_dst<<<80, 256, 0, stream>>>(pmaxv, pmaxj, sy, dstb, loss, cntG);
    {
        dim3 grid(20, 20);
        k_accum_lds<<<grid, 256, 0, stream>>>(sup, dstb, part);
    }
    k_reduce_proto<<<300, 64, 0, stream>>>(part, cntG, phatT);
    {
        dim3 grid(16, 30);
        k_qpartial<<<grid, 256, 0, stream>>>(qry, phatT, qmaxv, qrn);
    }
    k_pred<<<16, 256, 0, stream>>>(qmaxv, qrn, qy, out, loss, cbuf, lbuf);
    k_final<<<16, 256, 0, stream>>>(cbuf, lbuf, loss, out);
}